// Round 5
// baseline (562.189 us; speedup 1.0000x reference)
//
#include <hip/hip_runtime.h>

// VectorQuantizer: x (4,256,16,32,32) f32, weight (1024,256) f32.
// out[n*256+c] = weight[argmin_k d_np(n,k)][c], n in BTHW token order.
//
// Contract (R3, passed absmax 0): replicate numpy fp32 bit-for-bit:
//   sx/sw = np pairwise sumsq; m = sgemm sequential fma chain ascending c;
//   d = fl(fl(sx+sw) - 2m); argmin first-index.
// R4/R5 (passed): bf16-MFMA 3-product screen (err ~5e-5 << MARGIN=4e-4)
//   + exact resolve of near-ties.
// R6/R7 (passed, 370us): screen v2 — LDS double-buffer B; A "in regs" but
//   VGPR=100 proved the compiler rematerialized A loads per kt.
// R8/R9 (passed, 445us): screen v3 barrier-free; VGPR=92 — A STILL
//   remat'd per kt; now B also from L2 with 2 waves/SIMD -> latency-bound,
//   210us (worse than R7's 153). Root cause across R7-R9: hipcc silently
//   re-loads the 128-VGPR A set every iteration instead of keeping it live.
// R10: pin A fragments with opaque `asm volatile("" : "+v"(frag))` after
//   the one-time load — the frag's def becomes the asm, so remat of the
//   global load is impossible; compiler must carry A in VGPRs (~190-230
//   regs, fits 256 cap @ 2 waves/SIMD). Loop body: 16 B-loads + 48 MFMA.
//   Plus a block re-sync every 8 kt so the 4 waves share wf tiles in L1.
//   Numerics: identical MFMA operands/order/argmin -> same winners.

typedef __attribute__((ext_vector_type(8))) short bf16x8;
typedef __attribute__((ext_vector_type(4))) float f32x4;

#define MARGIN 4e-4f

// Opaque pin: redefines the value via empty asm so the compiler cannot
// rematerialize the originating load; forces register residency.
#define PIN(v) asm volatile("" : "+v"(v))

__device__ __forceinline__ unsigned short bf16_rne(float f) {
    unsigned int u = __float_as_uint(f);
    unsigned int r = u + 0x7fffu + ((u >> 16) & 1u);
    return (unsigned short)(r >> 16);
}
__device__ __forceinline__ float bf16_to_f(unsigned short h) {
    return __uint_as_float(((unsigned int)h) << 16);
}

// ---- numpy pairwise sum of squares, n=256, contract OFF ----
__device__ __forceinline__ float np_sumsq_256(const float* __restrict__ p,
                                              long stride) {
#pragma clang fp contract(off)
    float half[2];
    #pragma unroll
    for (int h = 0; h < 2; ++h) {
        const float* q = p + (long)h * 128 * stride;
        float r[8];
        #pragma unroll
        for (int j = 0; j < 8; ++j) { float v = q[(long)j * stride]; r[j] = v * v; }
        for (int i = 8; i < 128; i += 8) {
            #pragma unroll
            for (int j = 0; j < 8; ++j) {
                float v = q[(long)(i + j) * stride];
                r[j] = r[j] + v * v;
            }
        }
        half[h] = ((r[0] + r[1]) + (r[2] + r[3])) + ((r[4] + r[5]) + (r[6] + r[7]));
    }
    return half[0] + half[1];
}

__global__ __launch_bounds__(256) void vq_sxq(const float* __restrict__ x,
                                              float* __restrict__ sxq) {
    const int n = blockIdx.x * 256 + threadIdx.x;
    const int b = n >> 14, thw = n & 16383;
    sxq[n] = np_sumsq_256(x + (long)b * 4194304 + thw, 16384);
}

__global__ __launch_bounds__(256) void vq_swq(const float* __restrict__ w,
                                              float* __restrict__ swq) {
    const int k = blockIdx.x * 256 + threadIdx.x;
    swq[k] = np_sumsq_256(w + (long)k * 256, 1);
}

// ---- W transpose Wt[c][k] (used by resolve v2 and the R3 fallback) ----
__global__ __launch_bounds__(64) void vq_wt(const float* __restrict__ w,
                                            float* __restrict__ wt) {
    const int k = blockIdx.x;
    const int lane = threadIdx.x;
    const float4 v = reinterpret_cast<const float4*>(w + (size_t)k * 256)[lane];
    wt[(size_t)(4 * lane + 0) * 1024 + k] = v.x;
    wt[(size_t)(4 * lane + 1) * 1024 + k] = v.y;
    wt[(size_t)(4 * lane + 2) * 1024 + k] = v.z;
    wt[(size_t)(4 * lane + 3) * 1024 + k] = v.w;
}

// ---- pack W into MFMA-fragment-linear bf16 hi/lo planes ----
// wf layout: tile kt (16 codes) = 8192 ushorts; within: cs*1024 +
// plane*512 + (lq*128 + l15*8), holding w[kt*16+l15][cs*32+lq*8 .. +8].
__global__ __launch_bounds__(256) void vq_wfrag(const float* __restrict__ w,
                                                unsigned short* __restrict__ wf) {
    const int T = blockIdx.x * 256 + threadIdx.x;     // [0, 32768)
    const int l15 = T & 15, lq = (T >> 4) & 3, cs = (T >> 6) & 7, kt = T >> 9;
    const float* src = w + (size_t)(kt * 16 + l15) * 256 + cs * 32 + lq * 8;
    bf16x8 vh, vl;
    #pragma unroll
    for (int e = 0; e < 8; ++e) {
        const float v = src[e];
        const unsigned short h = bf16_rne(v);
        vh[e] = (short)h;
        vl[e] = (short)bf16_rne(v - bf16_to_f(h));
    }
    unsigned short* dst = wf + (size_t)kt * 8192 + cs * 1024 + (lq * 128 + l15 * 8);
    *(bf16x8*)dst = vh;
    *(bf16x8*)(dst + 512) = vl;
}

// ---- split + transpose x into MFMA-fragment-linear bf16 planes xf ----
// xf layout: 16-token tile T = n>>4: 8192 ushorts; within: cs*1024 +
// plane*512 + lq*128 + (n&15)*8, holding x_tok[n][cs*32+lq*8 .. +8].
__global__ __launch_bounds__(256) void vq_split_x(const float* __restrict__ x,
                                                  unsigned short* __restrict__ xf) {
    __shared__ float tile[64][68];   // stride 68: 16B-aligned float4 rows
    const int bid = blockIdx.x;
    const int b  = bid >> 10;
    const int ct = (bid >> 8) & 3;
    const int tt = bid & 255;
    const float* xb = x + (size_t)b * 4194304 + (size_t)(ct * 64) * 16384 + tt * 64;
    const int t4 = (threadIdx.x & 15) * 4;
    const int cg = threadIdx.x >> 4;   // 0..15
    #pragma unroll
    for (int i = 0; i < 4; ++i) {
        const int cc = i * 16 + cg;
        *(float4*)&tile[cc][t4] = *(const float4*)(xb + (size_t)cc * 16384 + t4);
    }
    __syncthreads();
    const int co = threadIdx.x & 7;    // channel group of 8
    const int tg = threadIdx.x >> 3;   // 0..31 (token pairs)
    const int cs = ct * 2 + (co >> 2);
    const int lq = co & 3;
    #pragma unroll
    for (int i = 0; i < 2; ++i) {
        const int t = tg * 2 + i;
        bf16x8 vh, vl;
        #pragma unroll
        for (int ee = 0; ee < 8; ++ee) {
            const int e = (ee + co) & 7;   // rotate e by co: spreads LDS banks
            const float v = tile[co * 8 + e][t];
            const unsigned short h = bf16_rne(v);
            vh[e] = (short)h;
            vl[e] = (short)bf16_rne(v - bf16_to_f(h));
        }
        const size_t T = (size_t)b * 1024 + tt * 4 + (t >> 4);
        unsigned short* dst = xf + T * 8192 + cs * 1024 + lq * 128 + (t & 15) * 8;
        *(bf16x8*)dst = vh;
        *(bf16x8*)(dst + 512) = vl;
    }
}

// ---- screen v4: A pinned register-resident, B streamed from wf ----
// Wave = 32 tokens (2 subtiles of 16) x all 1024 codes (64 kt-tiles of 16).
// Per (token,code) the acc chain (cs ascending; hh,lh,hl) is bitwise-
// identical to R5/R6's screen.
__global__ __launch_bounds__(256, 2) void vq_screen4(const unsigned short* __restrict__ xf,
                                                     const unsigned short* __restrict__ wf,
                                                     const float* __restrict__ swq,
                                                     int* __restrict__ winner,
                                                     int* __restrict__ flag,
                                                     int* __restrict__ count) {
    __shared__ __align__(16) float sw_s[1024];

    const int tid  = threadIdx.x;
    const int wv   = tid >> 6;
    const int lane = tid & 63;
    const int l15  = lane & 15, lq = lane >> 4;
    const int n0   = blockIdx.x * 128 + wv * 32;   // wave's first token

    reinterpret_cast<float4*>(sw_s)[tid] = reinterpret_cast<const float4*>(swq)[tid];
    __syncthreads();

    // A fragments: coalesced one-time loads from fragment-linear xf, then
    // PINNED so the compiler cannot rematerialize them inside the kt loop.
    bf16x8 ah0[8], al0[8], ah1[8], al1[8];
    {
        const unsigned short* ap = xf + (size_t)(n0 >> 4) * 8192 + lane * 8;
        #pragma unroll
        for (int cs = 0; cs < 8; ++cs) {
            ah0[cs] = *(const bf16x8*)(ap + cs * 1024);
            al0[cs] = *(const bf16x8*)(ap + cs * 1024 + 512);
            ah1[cs] = *(const bf16x8*)(ap + 8192 + cs * 1024);
            al1[cs] = *(const bf16x8*)(ap + 8192 + cs * 1024 + 512);
        }
        #pragma unroll
        for (int cs = 0; cs < 8; ++cs) {
            PIN(ah0[cs]); PIN(al0[cs]); PIN(ah1[cs]); PIN(al1[cs]);
        }
    }

    float m1[8], m2[8];
    int   i1[8];
    #pragma unroll
    for (int j = 0; j < 8; ++j) { m1[j] = 1e30f; m2[j] = 1e30f; i1[j] = 0; }

    const unsigned short* bp = wf + lane * 8;
    for (int kt = 0; kt < 64; ++kt) {
        f32x4 acc0 = (f32x4){0.f, 0.f, 0.f, 0.f};
        f32x4 acc1 = (f32x4){0.f, 0.f, 0.f, 0.f};
        #pragma unroll
        for (int cs = 0; cs < 8; ++cs) {
            const bf16x8 bh = *(const bf16x8*)(bp + cs * 1024);
            const bf16x8 bl = *(const bf16x8*)(bp + cs * 1024 + 512);
            acc0 = __builtin_amdgcn_mfma_f32_16x16x32_bf16(ah0[cs], bh, acc0, 0, 0, 0);
            acc0 = __builtin_amdgcn_mfma_f32_16x16x32_bf16(al0[cs], bh, acc0, 0, 0, 0);
            acc0 = __builtin_amdgcn_mfma_f32_16x16x32_bf16(ah0[cs], bl, acc0, 0, 0, 0);
            acc1 = __builtin_amdgcn_mfma_f32_16x16x32_bf16(ah1[cs], bh, acc1, 0, 0, 0);
            acc1 = __builtin_amdgcn_mfma_f32_16x16x32_bf16(al1[cs], bh, acc1, 0, 0, 0);
            acc1 = __builtin_amdgcn_mfma_f32_16x16x32_bf16(ah1[cs], bl, acc1, 0, 0, 0);
        }
        bp += 8192;

        const int k = kt * 16 + l15;      // C/D col = l15
        const float snk = sw_s[k];
        #pragma unroll
        for (int r = 0; r < 4; ++r) {
            const float d0 = fmaf(-2.f, acc0[r], snk);
            if (d0 < m1[r]) { m2[r] = m1[r]; m1[r] = d0; i1[r] = k; }
            else            m2[r] = fminf(m2[r], d0);
            const float d1 = fmaf(-2.f, acc1[r], snk);
            if (d1 < m1[4 + r]) { m2[4 + r] = m1[4 + r]; m1[4 + r] = d1; i1[4 + r] = k; }
            else                m2[4 + r] = fminf(m2[4 + r], d1);
        }

        // keep the block's 4 waves in phase every 8 tiles: shared wf tile
        // window stays L1-resident (16KB/tile, 32KB L1).
        if ((kt & 7) == 7) __syncthreads();
    }

    // reduce across the 16 l15 lanes (lane's codes are ≡ l15 mod 16)
    #pragma unroll
    for (int mm = 1; mm < 16; mm <<= 1) {
        #pragma unroll
        for (int j = 0; j < 8; ++j) {
            const float om1 = __shfl_xor(m1[j], mm);
            const int   oi1 = __shfl_xor(i1[j], mm);
            const float om2 = __shfl_xor(m2[j], mm);
            if (om1 < m1[j]) { m2[j] = fminf(m1[j], om2); m1[j] = om1; i1[j] = oi1; }
            else             { m2[j] = fminf(m2[j], om1); }
        }
    }
    // wave owns all codes for its tokens: no cross-wave merge needed.
    if (l15 == 0) {
        #pragma unroll
        for (int mt = 0; mt < 2; ++mt)
            #pragma unroll
            for (int r = 0; r < 4; ++r) {
                const int j = mt * 4 + r;
                const int n = n0 + mt * 16 + lq * 4 + r;
                if (m2[j] - m1[j] > MARGIN) {
                    winner[n] = i1[j];
                } else {
                    winner[n] = -1;
                    const int p = atomicAdd(count, 1);
                    flag[p] = n;
                }
            }
    }
}

// ---- resolve v2: np-exact rescore of flagged tokens, coalesced wt loads ----
__global__ __launch_bounds__(256) void vq_resolve2(const float* __restrict__ x,
                                                   const float* __restrict__ wt,
                                                   const float* __restrict__ sxq,
                                                   const float* __restrict__ swq,
                                                   const int* __restrict__ flag,
                                                   const int* __restrict__ count,
                                                   int* __restrict__ winner) {
    __shared__ float xsh[4][256];
    __shared__ int   toks[4];
    __shared__ float r_d[4][4];
    __shared__ int   r_k[4][4];

    const int cnt = *count;
    const int tid = threadIdx.x;
    const int groups = (cnt + 3) >> 2;

    for (int g = blockIdx.x; g < groups; g += gridDim.x) {
        if (tid < 4) toks[tid] = (4 * g + tid < cnt) ? flag[4 * g + tid] : -1;
        __syncthreads();
        #pragma unroll
        for (int i = 0; i < 4; i++) {
            const int n = toks[i];
            float v = 0.f;
            if (n >= 0) {
                const int b = n >> 14, thw = n & 16383;
                v = x[(size_t)b * 4194304 + (size_t)tid * 16384 + thw];
            }
            xsh[i][tid] = v;
        }
        __syncthreads();

        float acc[4][4];   // [q][token]
        #pragma unroll
        for (int q = 0; q < 4; q++)
            #pragma unroll
            for (int i = 0; i < 4; i++) acc[q][i] = 0.f;

        const float* wp = wt + tid;
        #pragma unroll 4
        for (int c = 0; c < 256; c++) {
            const float w0 = wp[(size_t)c * 1024 + 0];
            const float w1 = wp[(size_t)c * 1024 + 256];
            const float w2 = wp[(size_t)c * 1024 + 512];
            const float w3 = wp[(size_t)c * 1024 + 768];
            #pragma unroll
            for (int i = 0; i < 4; i++) {
                const float xc = xsh[i][c];
                acc[0][i] = fmaf(xc, w0, acc[0][i]);
                acc[1][i] = fmaf(xc, w1, acc[1][i]);
                acc[2][i] = fmaf(xc, w2, acc[2][i]);
                acc[3][i] = fmaf(xc, w3, acc[3][i]);
            }
        }

        // np distances + lexicographic (d,k) argmin per token
        const float swk[4] = {swq[tid], swq[tid + 256], swq[tid + 512], swq[tid + 768]};
        #pragma unroll
        for (int i = 0; i < 4; i++) {
            const int n = toks[i];
            float bd = 1e30f;
            int   bk = 0x7fffffff;
            if (n >= 0) {
                const float sx = sxq[n];
                #pragma unroll
                for (int q = 0; q < 4; q++) {
                    const int k = tid + 256 * q;
                    const float s1 = sx + swk[q];
                    const float d  = fmaf(-2.f, acc[q][i], s1);
                    if (d < bd || (d == bd && k < bk)) { bd = d; bk = k; }
                }
            }
            #pragma unroll
            for (int mm = 1; mm < 64; mm <<= 1) {
                const float od = __shfl_xor(bd, mm);
                const int   ok = __shfl_xor(bk, mm);
                if (od < bd || (od == bd && ok < bk)) { bd = od; bk = ok; }
            }
            if ((tid & 63) == 0) { r_d[tid >> 6][i] = bd; r_k[tid >> 6][i] = bk; }
        }
        __syncthreads();
        if (tid < 4) {
            const int n = toks[tid];
            if (n >= 0) {
                float bd = r_d[0][tid]; int bk = r_k[0][tid];
                #pragma unroll
                for (int wv = 1; wv < 4; wv++) {
                    const float od = r_d[wv][tid];
                    const int   ok = r_k[wv][tid];
                    if (od < bd || (od == bd && ok < bk)) { bd = od; bk = ok; }
                }
                winner[n] = bk;
            }
        }
        __syncthreads();
    }
}

// ---- gather ----
__global__ __launch_bounds__(256) void vq_gather(const float* __restrict__ w,
                                                 const int* __restrict__ winner,
                                                 float* __restrict__ out) {
    const size_t idx = (size_t)blockIdx.x * 256 + threadIdx.x;
    const int n = (int)(idx >> 6);
    const int c4 = (int)(idx & 63);
    reinterpret_cast<float4*>(out)[idx] =
        reinterpret_cast<const float4*>(w + (size_t)winner[n] * 256)[c4];
}

// ================= R3 fallback (proven-correct) =================
#define TPB 32
__global__ __launch_bounds__(256) void vq_main(const float* __restrict__ x,
                                               const float* __restrict__ sxq,
                                               const float* __restrict__ swq,
                                               const float* __restrict__ wt,
                                               const float* __restrict__ weight,
                                               float* __restrict__ out) {
    __shared__ __align__(16) float xs[256 * TPB];
    __shared__ float wn[1024];
    __shared__ float sxs[TPB];
    __shared__ float red_s[4][TPB];
    __shared__ int   red_i[4][TPB];
    __shared__ int   fidx[TPB];

    const int tid = threadIdx.x;
    const int n0 = blockIdx.x * TPB;
    const int b = n0 >> 14, thw = n0 & 16383;
    const float* xb = x + (size_t)b * 4194304 + thw;

    for (int i = tid; i < 256 * TPB; i += 256) {
        int t = i & (TPB - 1);
        int c = i >> 5;
        xs[c * TPB + t] = xb[(size_t)c * 16384 + t];
    }
    for (int i = tid; i < 1024; i += 256) wn[i] = swq[i];
    if (tid < TPB) sxs[tid] = sxq[n0 + tid];
    __syncthreads();

    const int lane = tid & 63, wv = tid >> 6;
    const int tg = lane & 7, cg = lane >> 3;
    float sxr[4];
    #pragma unroll
    for (int j = 0; j < 4; j++) sxr[j] = sxs[4 * tg + j];
    float bestS[4]; int bestI[4];
    #pragma unroll
    for (int j = 0; j < 4; j++) { bestS[j] = 1e30f; bestI[j] = 0x7fffffff; }

    for (int kb = 0; kb < 1024; kb += 256) {
        const int kbase = kb + 64 * wv + 8 * cg;
        float acc[4][8];
        #pragma unroll
        for (int j = 0; j < 4; j++)
            #pragma unroll
            for (int q = 0; q < 8; q++) acc[j][q] = 0.f;
        const float* wtp = wt + kbase;
        #pragma unroll 4
        for (int c = 0; c < 256; c++) {
            const float4 xv = *reinterpret_cast<const float4*>(&xs[c * TPB + 4 * tg]);
            const float4 w0 = *reinterpret_cast<const float4*>(wtp + (size_t)c * 1024);
            const float4 w1 = *reinterpret_cast<const float4*>(wtp + (size_t)c * 1024 + 4);
            const float xr[4] = {xv.x, xv.y, xv.z, xv.w};
            const float wr[8] = {w0.x, w0.y, w0.z, w0.w, w1.x, w1.y, w1.z, w1.w};
            #pragma unroll
            for (int j = 0; j < 4; j++)
                #pragma unroll
                for (int q = 0; q < 8; q++)
                    acc[j][q] = fmaf(xr[j], wr[q], acc[j][q]);
        }
        #pragma unroll
        for (int q = 0; q < 8; q++) {
            const int k = kbase + q;
            const float wnk = wn[k];
            #pragma unroll
            for (int j = 0; j < 4; j++) {
                const float s1 = sxr[j] + wnk;
                const float d = fmaf(-2.f, acc[j][q], s1);
                if (d < bestS[j]) { bestS[j] = d; bestI[j] = k; }
            }
        }
    }
    #pragma unroll
    for (int m = 8; m < 64; m <<= 1) {
        #pragma unroll
        for (int j = 0; j < 4; j++) {
            const float os = __shfl_xor(bestS[j], m);
            const int   oi = __shfl_xor(bestI[j], m);
            if (os < bestS[j] || (os == bestS[j] && oi < bestI[j])) {
                bestS[j] = os; bestI[j] = oi;
            }
        }
    }
    if (cg == 0) {
        #pragma unroll
        for (int j = 0; j < 4; j++) {
            red_s[wv][4 * tg + j] = bestS[j];
            red_i[wv][4 * tg + j] = bestI[j];
        }
    }
    __syncthreads();
    if (tid < TPB) {
        float bs = red_s[0][tid]; int bi = red_i[0][tid];
        #pragma unroll
        for (int w2 = 1; w2 < 4; w2++) {
            const float s2 = red_s[w2][tid];
            const int   i2 = red_i[w2][tid];
            if (s2 < bs || (s2 == bs && i2 < bi)) { bs = s2; bi = i2; }
        }
        fidx[tid] = bi;
    }
    __syncthreads();
    for (int i = tid; i < TPB * 256; i += 256) {
        const int t = i >> 8, c = i & 255;
        out[(size_t)(n0 + t) * 256 + c] = weight[(size_t)fidx[t] * 256 + c];
    }
}

// ================= launch =================
extern "C" void kernel_launch(void* const* d_in, const int* in_sizes, int n_in,
                              void* d_out, int out_size, void* d_ws, size_t ws_size,
                              hipStream_t stream) {
    const float* x = (const float*)d_in[0];
    const float* w = (const float*)d_in[1];
    float* out = (float*)d_out;

    char* p = (char*)d_ws;
    int*   count  = (int*)p;                         p += 256;
    int*   winner = (int*)p;                         p += 65536 * 4;
    int*   flag   = (int*)p;                         p += 65536 * 4;
    float* sxq    = (float*)p;                       p += 65536 * 4;
    float* swq    = (float*)p;                       p += 1024 * 4;
    float* wt     = (float*)p;                       p += 262144 * 4;
    unsigned short* wf = (unsigned short*)p;         p += 524288 * 2;
    unsigned short* xf = (unsigned short*)p;         p += 33554432 * 2;
    const size_t need_fast = (size_t)(p - (char*)d_ws);

    if (ws_size >= need_fast) {
        hipMemsetAsync(count, 0, 4, stream);
        vq_sxq<<<256, 256, 0, stream>>>(x, sxq);
        vq_swq<<<4, 256, 0, stream>>>(w, swq);
        vq_wt<<<1024, 64, 0, stream>>>(w, wt);
        vq_wfrag<<<128, 256, 0, stream>>>(w, wf);
        vq_split_x<<<4096, 256, 0, stream>>>(x, xf);
        vq_screen4<<<512, 256, 0, stream>>>(xf, wf, swq, winner, flag, count);
        vq_resolve2<<<1024, 256, 0, stream>>>(x, wt, sxq, swq, flag, count, winner);
        vq_gather<<<16384, 256, 0, stream>>>(w, winner, out);
    } else {
        // proven R3 fallback (needs ~1.3 MB)
        float* sxq2 = (float*)d_ws;
        float* swq2 = sxq2 + 65536;
        float* wt2  = swq2 + 1024;
        vq_sxq<<<256, 256, 0, stream>>>(x, sxq2);
        vq_swq<<<4, 256, 0, stream>>>(w, swq2);
        vq_wt<<<1024, 64, 0, stream>>>(w, wt2);
        vq_main<<<65536 / TPB, 256, 0, stream>>>(x, sxq2, swq2, wt2, w, out);
    }
}

// Round 6
// 367.317 us; speedup vs baseline: 1.5305x; 1.5305x over previous
//
#include <hip/hip_runtime.h>

// VectorQuantizer: x (4,256,16,32,32) f32, weight (1024,256) f32.
// out[n*256+c] = weight[argmin_k d_np(n,k)][c], n in BTHW token order.
//
// Contract (R3, passed absmax 0): replicate numpy fp32 bit-for-bit:
//   sx/sw = np pairwise sumsq; m = sgemm sequential fma chain ascending c;
//   d = fl(fl(sx+sw) - 2m); argmin first-index.
// R4/R5 (passed): bf16-MFMA 3-product screen (err ~5e-5 << MARGIN=4e-4)
//   + exact resolve of near-ties.
// R6/R7 (passed, 370us; screen 153us): LDS-dbuf B + "A in regs" (remat'd).
// R8/R9 (passed, 445us; screen 210us): barrier-free B-from-L2 — worse.
// R10 (passed, 562us; screen 325us): PIN forced scratch spill (VGPR=88).
// POST-MORTEM R7-R10: occupancy was grid-capped all along: 512 blocks x 4
//   waves = 2048 waves = exactly 2 waves/SIMD; every L2/LDS latency chain
//   exposed. A-state (128 VGPR) also too big for the allocator to keep.
// R11: R7's proven dbuf structure with 16 tokens/wave: grid 1024 (4096
//   waves -> up to 4/SIMD), A = 64 VGPR (allocator keeps it naturally, no
//   PIN), launch_bounds(256,3) for headroom (cap ~170), wave owns all
//   codes for its 16 tokens so the cross-wave merge disappears.
//   Numerics: identical MFMA chain (cs asc; hh,lh,hl) + top-2/MARGIN.

typedef __attribute__((ext_vector_type(8))) short bf16x8;
typedef __attribute__((ext_vector_type(4))) float f32x4;

#define MARGIN 4e-4f

__device__ __forceinline__ unsigned short bf16_rne(float f) {
    unsigned int u = __float_as_uint(f);
    unsigned int r = u + 0x7fffu + ((u >> 16) & 1u);
    return (unsigned short)(r >> 16);
}
__device__ __forceinline__ float bf16_to_f(unsigned short h) {
    return __uint_as_float(((unsigned int)h) << 16);
}

// ---- numpy pairwise sum of squares, n=256, contract OFF ----
__device__ __forceinline__ float np_sumsq_256(const float* __restrict__ p,
                                              long stride) {
#pragma clang fp contract(off)
    float half[2];
    #pragma unroll
    for (int h = 0; h < 2; ++h) {
        const float* q = p + (long)h * 128 * stride;
        float r[8];
        #pragma unroll
        for (int j = 0; j < 8; ++j) { float v = q[(long)j * stride]; r[j] = v * v; }
        for (int i = 8; i < 128; i += 8) {
            #pragma unroll
            for (int j = 0; j < 8; ++j) {
                float v = q[(long)(i + j) * stride];
                r[j] = r[j] + v * v;
            }
        }
        half[h] = ((r[0] + r[1]) + (r[2] + r[3])) + ((r[4] + r[5]) + (r[6] + r[7]));
    }
    return half[0] + half[1];
}

__global__ __launch_bounds__(256) void vq_sxq(const float* __restrict__ x,
                                              float* __restrict__ sxq) {
    const int n = blockIdx.x * 256 + threadIdx.x;
    const int b = n >> 14, thw = n & 16383;
    sxq[n] = np_sumsq_256(x + (long)b * 4194304 + thw, 16384);
}

__global__ __launch_bounds__(256) void vq_swq(const float* __restrict__ w,
                                              float* __restrict__ swq) {
    const int k = blockIdx.x * 256 + threadIdx.x;
    swq[k] = np_sumsq_256(w + (long)k * 256, 1);
}

// ---- W transpose Wt[c][k] (used by resolve v2 and the R3 fallback) ----
__global__ __launch_bounds__(64) void vq_wt(const float* __restrict__ w,
                                            float* __restrict__ wt) {
    const int k = blockIdx.x;
    const int lane = threadIdx.x;
    const float4 v = reinterpret_cast<const float4*>(w + (size_t)k * 256)[lane];
    wt[(size_t)(4 * lane + 0) * 1024 + k] = v.x;
    wt[(size_t)(4 * lane + 1) * 1024 + k] = v.y;
    wt[(size_t)(4 * lane + 2) * 1024 + k] = v.z;
    wt[(size_t)(4 * lane + 3) * 1024 + k] = v.w;
}

// ---- pack W into MFMA-fragment-linear bf16 hi/lo planes ----
// wf layout: tile kt (16 codes) = 8192 ushorts; within: cs*1024 +
// plane*512 + (lq*128 + l15*8), holding w[kt*16+l15][cs*32+lq*8 .. +8].
__global__ __launch_bounds__(256) void vq_wfrag(const float* __restrict__ w,
                                                unsigned short* __restrict__ wf) {
    const int T = blockIdx.x * 256 + threadIdx.x;     // [0, 32768)
    const int l15 = T & 15, lq = (T >> 4) & 3, cs = (T >> 6) & 7, kt = T >> 9;
    const float* src = w + (size_t)(kt * 16 + l15) * 256 + cs * 32 + lq * 8;
    bf16x8 vh, vl;
    #pragma unroll
    for (int e = 0; e < 8; ++e) {
        const float v = src[e];
        const unsigned short h = bf16_rne(v);
        vh[e] = (short)h;
        vl[e] = (short)bf16_rne(v - bf16_to_f(h));
    }
    unsigned short* dst = wf + (size_t)kt * 8192 + cs * 1024 + (lq * 128 + l15 * 8);
    *(bf16x8*)dst = vh;
    *(bf16x8*)(dst + 512) = vl;
}

// ---- split + transpose x into MFMA-fragment-linear bf16 planes xf ----
// xf layout: 16-token tile T = n>>4: 8192 ushorts; within: cs*1024 +
// plane*512 + lq*128 + (n&15)*8, holding x_tok[n][cs*32+lq*8 .. +8].
__global__ __launch_bounds__(256) void vq_split_x(const float* __restrict__ x,
                                                  unsigned short* __restrict__ xf) {
    __shared__ float tile[64][68];   // stride 68: 16B-aligned float4 rows
    const int bid = blockIdx.x;
    const int b  = bid >> 10;
    const int ct = (bid >> 8) & 3;
    const int tt = bid & 255;
    const float* xb = x + (size_t)b * 4194304 + (size_t)(ct * 64) * 16384 + tt * 64;
    const int t4 = (threadIdx.x & 15) * 4;
    const int cg = threadIdx.x >> 4;   // 0..15
    #pragma unroll
    for (int i = 0; i < 4; ++i) {
        const int cc = i * 16 + cg;
        *(float4*)&tile[cc][t4] = *(const float4*)(xb + (size_t)cc * 16384 + t4);
    }
    __syncthreads();
    const int co = threadIdx.x & 7;    // channel group of 8
    const int tg = threadIdx.x >> 3;   // 0..31 (token pairs)
    const int cs = ct * 2 + (co >> 2);
    const int lq = co & 3;
    #pragma unroll
    for (int i = 0; i < 2; ++i) {
        const int t = tg * 2 + i;
        bf16x8 vh, vl;
        #pragma unroll
        for (int ee = 0; ee < 8; ++ee) {
            const int e = (ee + co) & 7;   // rotate e by co: spreads LDS banks
            const float v = tile[co * 8 + e][t];
            const unsigned short h = bf16_rne(v);
            vh[e] = (short)h;
            vl[e] = (short)bf16_rne(v - bf16_to_f(h));
        }
        const size_t T = (size_t)b * 1024 + tt * 4 + (t >> 4);
        unsigned short* dst = xf + T * 8192 + cs * 1024 + lq * 128 + (t & 15) * 8;
        *(bf16x8*)dst = vh;
        *(bf16x8*)(dst + 512) = vl;
    }
}

// ---- screen v5: 16 tokens/wave, LDS-dbuf B, grid 1024 (4 waves/SIMD) ----
// Block = 4 waves x 16 tokens = 64 tokens; each wave scans all 1024 codes
// (64 kt-tiles of 16) against its own 16 tokens. A = 16 bf16x8 = 64 VGPR.
// Per (token,code) the acc chain (cs ascending; hh,lh,hl) is bitwise-
// identical to R5-R10's screen.
__global__ __launch_bounds__(256, 3) void vq_screen5(const unsigned short* __restrict__ xf,
                                                     const unsigned short* __restrict__ wf,
                                                     const float* __restrict__ swq,
                                                     int* __restrict__ winner,
                                                     int* __restrict__ flag,
                                                     int* __restrict__ count) {
    __shared__ __align__(16) unsigned short btile[2][8192];  // 2 x 16 KB
    __shared__ __align__(16) float sw_s[1024];

    const int tid  = threadIdx.x;
    const int wv   = tid >> 6;
    const int lane = tid & 63;
    const int l15  = lane & 15, lq = lane >> 4;
    const int n0   = blockIdx.x * 64 + wv * 16;   // wave's first token

    reinterpret_cast<float4*>(sw_s)[tid] = reinterpret_cast<const float4*>(swq)[tid];

    // A fragments: one 16-token subtile, coalesced from fragment-linear xf.
    bf16x8 ah[8], al[8];
    {
        const unsigned short* ap = xf + (size_t)(n0 >> 4) * 8192 + lane * 8;
        #pragma unroll
        for (int cs = 0; cs < 8; ++cs) {
            ah[cs] = *(const bf16x8*)(ap + cs * 1024);
            al[cs] = *(const bf16x8*)(ap + cs * 1024 + 512);
        }
    }

    // prologue: stage tile kt=0 (4 KB per wave, linear copy)
    {
        const unsigned short* src = wf + wv * 2048 + lane * 8;
        unsigned short* dst = &btile[0][wv * 2048 + lane * 8];
        #pragma unroll
        for (int j = 0; j < 4; ++j)
            *(bf16x8*)(dst + j * 512) = *(const bf16x8*)(src + j * 512);
    }
    __syncthreads();

    float m1[4], m2[4];
    int   i1[4];
    #pragma unroll
    for (int j = 0; j < 4; ++j) { m1[j] = 1e30f; m2[j] = 1e30f; i1[j] = 0; }

    for (int kt = 0; kt < 64; ++kt) {
        const int cur = kt & 1;

        // issue next tile's global loads early (write-late below)
        bf16x8 stg[4];
        if (kt < 63) {
            const unsigned short* src = wf + (size_t)(kt + 1) * 8192 + wv * 2048 + lane * 8;
            #pragma unroll
            for (int j = 0; j < 4; ++j) stg[j] = *(const bf16x8*)(src + j * 512);
        }

        f32x4 acc = (f32x4){0.f, 0.f, 0.f, 0.f};
        const unsigned short* bp = &btile[cur][lane * 8];
        #pragma unroll
        for (int cs = 0; cs < 8; ++cs) {
            const bf16x8 bh = *(const bf16x8*)(bp + cs * 1024);
            const bf16x8 bl = *(const bf16x8*)(bp + cs * 1024 + 512);
            acc = __builtin_amdgcn_mfma_f32_16x16x32_bf16(ah[cs], bh, acc, 0, 0, 0);
            acc = __builtin_amdgcn_mfma_f32_16x16x32_bf16(al[cs], bh, acc, 0, 0, 0);
            acc = __builtin_amdgcn_mfma_f32_16x16x32_bf16(ah[cs], bl, acc, 0, 0, 0);
        }

        const int k = kt * 16 + l15;      // C/D col = l15
        const float snk = sw_s[k];
        #pragma unroll
        for (int r = 0; r < 4; ++r) {
            const float d = fmaf(-2.f, acc[r], snk);
            if (d < m1[r]) { m2[r] = m1[r]; m1[r] = d; i1[r] = k; }
            else           m2[r] = fminf(m2[r], d);
        }

        // write-late: park next tile into the other buffer, then barrier
        if (kt < 63) {
            unsigned short* dst = &btile[cur ^ 1][wv * 2048 + lane * 8];
            #pragma unroll
            for (int j = 0; j < 4; ++j) *(bf16x8*)(dst + j * 512) = stg[j];
        }
        __syncthreads();
    }

    // reduce across the 16 l15 lanes (lane's codes are ≡ l15 mod 16)
    #pragma unroll
    for (int mm = 1; mm < 16; mm <<= 1) {
        #pragma unroll
        for (int j = 0; j < 4; ++j) {
            const float om1 = __shfl_xor(m1[j], mm);
            const int   oi1 = __shfl_xor(i1[j], mm);
            const float om2 = __shfl_xor(m2[j], mm);
            if (om1 < m1[j]) { m2[j] = fminf(m1[j], om2); m1[j] = om1; i1[j] = oi1; }
            else             { m2[j] = fminf(m2[j], om1); }
        }
    }
    // wave owns all codes for its 16 tokens: winner is final here.
    if (l15 == 0) {
        #pragma unroll
        for (int r = 0; r < 4; ++r) {
            const int n = n0 + lq * 4 + r;   // token row = lq*4 + r
            if (m2[r] - m1[r] > MARGIN) {
                winner[n] = i1[r];
            } else {
                winner[n] = -1;
                const int p = atomicAdd(count, 1);
                flag[p] = n;
            }
        }
    }
}

// ---- resolve v2: np-exact rescore of flagged tokens, coalesced wt loads ----
__global__ __launch_bounds__(256) void vq_resolve2(const float* __restrict__ x,
                                                   const float* __restrict__ wt,
                                                   const float* __restrict__ sxq,
                                                   const float* __restrict__ swq,
                                                   const int* __restrict__ flag,
                                                   const int* __restrict__ count,
                                                   int* __restrict__ winner) {
    __shared__ float xsh[4][256];
    __shared__ int   toks[4];
    __shared__ float r_d[4][4];
    __shared__ int   r_k[4][4];

    const int cnt = *count;
    const int tid = threadIdx.x;
    const int groups = (cnt + 3) >> 2;

    for (int g = blockIdx.x; g < groups; g += gridDim.x) {
        if (tid < 4) toks[tid] = (4 * g + tid < cnt) ? flag[4 * g + tid] : -1;
        __syncthreads();
        #pragma unroll
        for (int i = 0; i < 4; i++) {
            const int n = toks[i];
            float v = 0.f;
            if (n >= 0) {
                const int b = n >> 14, thw = n & 16383;
                v = x[(size_t)b * 4194304 + (size_t)tid * 16384 + thw];
            }
            xsh[i][tid] = v;
        }
        __syncthreads();

        float acc[4][4];   // [q][token]
        #pragma unroll
        for (int q = 0; q < 4; q++)
            #pragma unroll
            for (int i = 0; i < 4; i++) acc[q][i] = 0.f;

        const float* wp = wt + tid;
        #pragma unroll 4
        for (int c = 0; c < 256; c++) {
            const float w0 = wp[(size_t)c * 1024 + 0];
            const float w1 = wp[(size_t)c * 1024 + 256];
            const float w2 = wp[(size_t)c * 1024 + 512];
            const float w3 = wp[(size_t)c * 1024 + 768];
            #pragma unroll
            for (int i = 0; i < 4; i++) {
                const float xc = xsh[i][c];
                acc[0][i] = fmaf(xc, w0, acc[0][i]);
                acc[1][i] = fmaf(xc, w1, acc[1][i]);
                acc[2][i] = fmaf(xc, w2, acc[2][i]);
                acc[3][i] = fmaf(xc, w3, acc[3][i]);
            }
        }

        // np distances + lexicographic (d,k) argmin per token
        const float swk[4] = {swq[tid], swq[tid + 256], swq[tid + 512], swq[tid + 768]};
        #pragma unroll
        for (int i = 0; i < 4; i++) {
            const int n = toks[i];
            float bd = 1e30f;
            int   bk = 0x7fffffff;
            if (n >= 0) {
                const float sx = sxq[n];
                #pragma unroll
                for (int q = 0; q < 4; q++) {
                    const int k = tid + 256 * q;
                    const float s1 = sx + swk[q];
                    const float d  = fmaf(-2.f, acc[q][i], s1);
                    if (d < bd || (d == bd && k < bk)) { bd = d; bk = k; }
                }
            }
            #pragma unroll
            for (int mm = 1; mm < 64; mm <<= 1) {
                const float od = __shfl_xor(bd, mm);
                const int   ok = __shfl_xor(bk, mm);
                if (od < bd || (od == bd && ok < bk)) { bd = od; bk = ok; }
            }
            if ((tid & 63) == 0) { r_d[tid >> 6][i] = bd; r_k[tid >> 6][i] = bk; }
        }
        __syncthreads();
        if (tid < 4) {
            const int n = toks[tid];
            if (n >= 0) {
                float bd = r_d[0][tid]; int bk = r_k[0][tid];
                #pragma unroll
                for (int wv = 1; wv < 4; wv++) {
                    const float od = r_d[wv][tid];
                    const int   ok = r_k[wv][tid];
                    if (od < bd || (od == bd && ok < bk)) { bd = od; bk = ok; }
                }
                winner[n] = bk;
            }
        }
        __syncthreads();
    }
}

// ---- gather ----
__global__ __launch_bounds__(256) void vq_gather(const float* __restrict__ w,
                                                 const int* __restrict__ winner,
                                                 float* __restrict__ out) {
    const size_t idx = (size_t)blockIdx.x * 256 + threadIdx.x;
    const int n = (int)(idx >> 6);
    const int c4 = (int)(idx & 63);
    reinterpret_cast<float4*>(out)[idx] =
        reinterpret_cast<const float4*>(w + (size_t)winner[n] * 256)[c4];
}

// ================= R3 fallback (proven-correct) =================
#define TPB 32
__global__ __launch_bounds__(256) void vq_main(const float* __restrict__ x,
                                               const float* __restrict__ sxq,
                                               const float* __restrict__ swq,
                                               const float* __restrict__ wt,
                                               const float* __restrict__ weight,
                                               float* __restrict__ out) {
    __shared__ __align__(16) float xs[256 * TPB];
    __shared__ float wn[1024];
    __shared__ float sxs[TPB];
    __shared__ float red_s[4][TPB];
    __shared__ int   red_i[4][TPB];
    __shared__ int   fidx[TPB];

    const int tid = threadIdx.x;
    const int n0 = blockIdx.x * TPB;
    const int b = n0 >> 14, thw = n0 & 16383;
    const float* xb = x + (size_t)b * 4194304 + thw;

    for (int i = tid; i < 256 * TPB; i += 256) {
        int t = i & (TPB - 1);
        int c = i >> 5;
        xs[c * TPB + t] = xb[(size_t)c * 16384 + t];
    }
    for (int i = tid; i < 1024; i += 256) wn[i] = swq[i];
    if (tid < TPB) sxs[tid] = sxq[n0 + tid];
    __syncthreads();

    const int lane = tid & 63, wv = tid >> 6;
    const int tg = lane & 7, cg = lane >> 3;
    float sxr[4];
    #pragma unroll
    for (int j = 0; j < 4; j++) sxr[j] = sxs[4 * tg + j];
    float bestS[4]; int bestI[4];
    #pragma unroll
    for (int j = 0; j < 4; j++) { bestS[j] = 1e30f; bestI[j] = 0x7fffffff; }

    for (int kb = 0; kb < 1024; kb += 256) {
        const int kbase = kb + 64 * wv + 8 * cg;
        float acc[4][8];
        #pragma unroll
        for (int j = 0; j < 4; j++)
            #pragma unroll
            for (int q = 0; q < 8; q++) acc[j][q] = 0.f;
        const float* wtp = wt + kbase;
        #pragma unroll 4
        for (int c = 0; c < 256; c++) {
            const float4 xv = *reinterpret_cast<const float4*>(&xs[c * TPB + 4 * tg]);
            const float4 w0 = *reinterpret_cast<const float4*>(wtp + (size_t)c * 1024);
            const float4 w1 = *reinterpret_cast<const float4*>(wtp + (size_t)c * 1024 + 4);
            const float xr[4] = {xv.x, xv.y, xv.z, xv.w};
            const float wr[8] = {w0.x, w0.y, w0.z, w0.w, w1.x, w1.y, w1.z, w1.w};
            #pragma unroll
            for (int j = 0; j < 4; j++)
                #pragma unroll
                for (int q = 0; q < 8; q++)
                    acc[j][q] = fmaf(xr[j], wr[q], acc[j][q]);
        }
        #pragma unroll
        for (int q = 0; q < 8; q++) {
            const int k = kbase + q;
            const float wnk = wn[k];
            #pragma unroll
            for (int j = 0; j < 4; j++) {
                const float s1 = sxr[j] + wnk;
                const float d = fmaf(-2.f, acc[j][q], s1);
                if (d < bestS[j]) { bestS[j] = d; bestI[j] = k; }
            }
        }
    }
    #pragma unroll
    for (int m = 8; m < 64; m <<= 1) {
        #pragma unroll
        for (int j = 0; j < 4; j++) {
            const float os = __shfl_xor(bestS[j], m);
            const int   oi = __shfl_xor(bestI[j], m);
            if (os < bestS[j] || (os == bestS[j] && oi < bestI[j])) {
                bestS[j] = os; bestI[j] = oi;
            }
        }
    }
    if (cg == 0) {
        #pragma unroll
        for (int j = 0; j < 4; j++) {
            red_s[wv][4 * tg + j] = bestS[j];
            red_i[wv][4 * tg + j] = bestI[j];
        }
    }
    __syncthreads();
    if (tid < TPB) {
        float bs = red_s[0][tid]; int bi = red_i[0][tid];
        #pragma unroll
        for (int w2 = 1; w2 < 4; w2++) {
            const float s2 = red_s[w2][tid];
            const int   i2 = red_i[w2][tid];
            if (s2 < bs || (s2 == bs && i2 < bi)) { bs = s2; bi = i2; }
        }
        fidx[tid] = bi;
    }
    __syncthreads();
    for (int i = tid; i < TPB * 256; i += 256) {
        const int t = i >> 8, c = i & 255;
        out[(size_t)(n0 + t) * 256 + c] = weight[(size_t)fidx[t] * 256 + c];
    }
}

// ================= launch =================
extern "C" void kernel_launch(void* const* d_in, const int* in_sizes, int n_in,
                              void* d_out, int out_size, void* d_ws, size_t ws_size,
                              hipStream_t stream) {
    const float* x = (const float*)d_in[0];
    const float* w = (const float*)d_in[1];
    float* out = (float*)d_out;

    char* p = (char*)d_ws;
    int*   count  = (int*)p;                         p += 256;
    int*   winner = (int*)p;                         p += 65536 * 4;
    int*   flag   = (int*)p;                         p += 65536 * 4;
    float* sxq    = (float*)p;                       p += 65536 * 4;
    float* swq    = (float*)p;                       p += 1024 * 4;
    float* wt     = (float*)p;                       p += 262144 * 4;
    unsigned short* wf = (unsigned short*)p;         p += 524288 * 2;
    unsigned short* xf = (unsigned short*)p;         p += 33554432 * 2;
    const size_t need_fast = (size_t)(p - (char*)d_ws);

    if (ws_size >= need_fast) {
        hipMemsetAsync(count, 0, 4, stream);
        vq_sxq<<<256, 256, 0, stream>>>(x, sxq);
        vq_swq<<<4, 256, 0, stream>>>(w, swq);
        vq_wt<<<1024, 64, 0, stream>>>(w, wt);
        vq_wfrag<<<128, 256, 0, stream>>>(w, wf);
        vq_split_x<<<4096, 256, 0, stream>>>(x, xf);
        vq_screen5<<<1024, 256, 0, stream>>>(xf, wf, swq, winner, flag, count);
        vq_resolve2<<<1024, 256, 0, stream>>>(x, wt, sxq, swq, flag, count, winner);
        vq_gather<<<16384, 256, 0, stream>>>(w, winner, out);
    } else {
        // proven R3 fallback (needs ~1.3 MB)
        float* sxq2 = (float*)d_ws;
        float* swq2 = sxq2 + 65536;
        float* wt2  = swq2 + 1024;
        vq_sxq<<<256, 256, 0, stream>>>(x, sxq2);
        vq_swq<<<4, 256, 0, stream>>>(w, swq2);
        vq_wt<<<1024, 64, 0, stream>>>(w, wt2);
        vq_main<<<65536 / TPB, 256, 0, stream>>>(x, sxq2, swq2, wt2, w, out);
    }
}

// Round 7
// 364.971 us; speedup vs baseline: 1.5404x; 1.0064x over previous
//
#include <hip/hip_runtime.h>

// VectorQuantizer: x (4,256,16,32,32) f32, weight (1024,256) f32.
// out[n*256+c] = weight[argmin_k d_np(n,k)][c], n in BTHW token order.
//
// Contract (R3, passed absmax 0): replicate numpy fp32 bit-for-bit:
//   sx/sw = np pairwise sumsq; m = sgemm sequential fma chain ascending c;
//   d = fl(fl(sx+sw) - 2m); argmin first-index.
// R4/R5 (passed): bf16-MFMA 3-product screen (err ~5e-5 << MARGIN=4e-4)
//   + exact resolve of near-ties.
// R6/R7 (passed, 370us; screen 153us): LDS-dbuf B; A remat'd (VGPR=100).
// R8/R9 (passed, 445us; screen 210us): barrier-free B-from-L2 — worse.
// R10 (passed, 562us; screen 325us): "+v" PIN -> scratch spill (VGPR=88).
// R11 (passed, 367us; screen 130.7us): 16 tok/wave, grid 1024, occupancy
//   22->34%. But VGPR=60: even the 64-VGPR A-set is remat'd. Measured
//   130us == computed A-remat L2 traffic (16.8MB/CU @ ~56B/cyc). hipcc's
//   allocator ALWAYS re-loads loop-invariant data rather than keep it live.
// R12: pin A in AGPRs via `asm volatile("" : "+a"(frag))`. An asm def is
//   not rematerializable, and gfx950 MFMA reads A operands from AGPRs
//   directly (AV operand class) — so A becomes truly loop-resident with
//   zero per-use cost. 64 AGPR + ~60 VGPR = ~124 combined -> still 4
//   waves/SIMD. Single-variable change vs R11; numerics are a pure value
//   passthrough -> same winners bit-for-bit.

typedef __attribute__((ext_vector_type(8))) short bf16x8;
typedef __attribute__((ext_vector_type(4))) float f32x4;

#define MARGIN 4e-4f

__device__ __forceinline__ unsigned short bf16_rne(float f) {
    unsigned int u = __float_as_uint(f);
    unsigned int r = u + 0x7fffu + ((u >> 16) & 1u);
    return (unsigned short)(r >> 16);
}
__device__ __forceinline__ float bf16_to_f(unsigned short h) {
    return __uint_as_float(((unsigned int)h) << 16);
}

// ---- numpy pairwise sum of squares, n=256, contract OFF ----
__device__ __forceinline__ float np_sumsq_256(const float* __restrict__ p,
                                              long stride) {
#pragma clang fp contract(off)
    float half[2];
    #pragma unroll
    for (int h = 0; h < 2; ++h) {
        const float* q = p + (long)h * 128 * stride;
        float r[8];
        #pragma unroll
        for (int j = 0; j < 8; ++j) { float v = q[(long)j * stride]; r[j] = v * v; }
        for (int i = 8; i < 128; i += 8) {
            #pragma unroll
            for (int j = 0; j < 8; ++j) {
                float v = q[(long)(i + j) * stride];
                r[j] = r[j] + v * v;
            }
        }
        half[h] = ((r[0] + r[1]) + (r[2] + r[3])) + ((r[4] + r[5]) + (r[6] + r[7]));
    }
    return half[0] + half[1];
}

__global__ __launch_bounds__(256) void vq_sxq(const float* __restrict__ x,
                                              float* __restrict__ sxq) {
    const int n = blockIdx.x * 256 + threadIdx.x;
    const int b = n >> 14, thw = n & 16383;
    sxq[n] = np_sumsq_256(x + (long)b * 4194304 + thw, 16384);
}

__global__ __launch_bounds__(256) void vq_swq(const float* __restrict__ w,
                                              float* __restrict__ swq) {
    const int k = blockIdx.x * 256 + threadIdx.x;
    swq[k] = np_sumsq_256(w + (long)k * 256, 1);
}

// ---- W transpose Wt[c][k] (used by resolve v2 and the R3 fallback) ----
__global__ __launch_bounds__(64) void vq_wt(const float* __restrict__ w,
                                            float* __restrict__ wt) {
    const int k = blockIdx.x;
    const int lane = threadIdx.x;
    const float4 v = reinterpret_cast<const float4*>(w + (size_t)k * 256)[lane];
    wt[(size_t)(4 * lane + 0) * 1024 + k] = v.x;
    wt[(size_t)(4 * lane + 1) * 1024 + k] = v.y;
    wt[(size_t)(4 * lane + 2) * 1024 + k] = v.z;
    wt[(size_t)(4 * lane + 3) * 1024 + k] = v.w;
}

// ---- pack W into MFMA-fragment-linear bf16 hi/lo planes ----
// wf layout: tile kt (16 codes) = 8192 ushorts; within: cs*1024 +
// plane*512 + (lq*128 + l15*8), holding w[kt*16+l15][cs*32+lq*8 .. +8].
__global__ __launch_bounds__(256) void vq_wfrag(const float* __restrict__ w,
                                                unsigned short* __restrict__ wf) {
    const int T = blockIdx.x * 256 + threadIdx.x;     // [0, 32768)
    const int l15 = T & 15, lq = (T >> 4) & 3, cs = (T >> 6) & 7, kt = T >> 9;
    const float* src = w + (size_t)(kt * 16 + l15) * 256 + cs * 32 + lq * 8;
    bf16x8 vh, vl;
    #pragma unroll
    for (int e = 0; e < 8; ++e) {
        const float v = src[e];
        const unsigned short h = bf16_rne(v);
        vh[e] = (short)h;
        vl[e] = (short)bf16_rne(v - bf16_to_f(h));
    }
    unsigned short* dst = wf + (size_t)kt * 8192 + cs * 1024 + (lq * 128 + l15 * 8);
    *(bf16x8*)dst = vh;
    *(bf16x8*)(dst + 512) = vl;
}

// ---- split + transpose x into MFMA-fragment-linear bf16 planes xf ----
// xf layout: 16-token tile T = n>>4: 8192 ushorts; within: cs*1024 +
// plane*512 + lq*128 + (n&15)*8, holding x_tok[n][cs*32+lq*8 .. +8].
__global__ __launch_bounds__(256) void vq_split_x(const float* __restrict__ x,
                                                  unsigned short* __restrict__ xf) {
    __shared__ float tile[64][68];   // stride 68: 16B-aligned float4 rows
    const int bid = blockIdx.x;
    const int b  = bid >> 10;
    const int ct = (bid >> 8) & 3;
    const int tt = bid & 255;
    const float* xb = x + (size_t)b * 4194304 + (size_t)(ct * 64) * 16384 + tt * 64;
    const int t4 = (threadIdx.x & 15) * 4;
    const int cg = threadIdx.x >> 4;   // 0..15
    #pragma unroll
    for (int i = 0; i < 4; ++i) {
        const int cc = i * 16 + cg;
        *(float4*)&tile[cc][t4] = *(const float4*)(xb + (size_t)cc * 16384 + t4);
    }
    __syncthreads();
    const int co = threadIdx.x & 7;    // channel group of 8
    const int tg = threadIdx.x >> 3;   // 0..31 (token pairs)
    const int cs = ct * 2 + (co >> 2);
    const int lq = co & 3;
    #pragma unroll
    for (int i = 0; i < 2; ++i) {
        const int t = tg * 2 + i;
        bf16x8 vh, vl;
        #pragma unroll
        for (int ee = 0; ee < 8; ++ee) {
            const int e = (ee + co) & 7;   // rotate e by co: spreads LDS banks
            const float v = tile[co * 8 + e][t];
            const unsigned short h = bf16_rne(v);
            vh[e] = (short)h;
            vl[e] = (short)bf16_rne(v - bf16_to_f(h));
        }
        const size_t T = (size_t)b * 1024 + tt * 4 + (t >> 4);
        unsigned short* dst = xf + T * 8192 + cs * 1024 + lq * 128 + (t & 15) * 8;
        *(bf16x8*)dst = vh;
        *(bf16x8*)(dst + 512) = vl;
    }
}

// ---- screen v6: A pinned in AGPRs, LDS-dbuf B, grid 1024 ----
// Block = 4 waves x 16 tokens = 64 tokens; each wave scans all 1024 codes
// (64 kt-tiles of 16) against its own 16 tokens. A = 16 bf16x8 held in 64
// AGPRs (asm "a" pin — non-rematerializable def; MFMA reads AGPR direct).
// Per (token,code) the acc chain (cs ascending; hh,lh,hl) is bitwise-
// identical to R5-R11's screen.
__global__ __launch_bounds__(256, 3) void vq_screen6(const unsigned short* __restrict__ xf,
                                                     const unsigned short* __restrict__ wf,
                                                     const float* __restrict__ swq,
                                                     int* __restrict__ winner,
                                                     int* __restrict__ flag,
                                                     int* __restrict__ count) {
    __shared__ __align__(16) unsigned short btile[2][8192];  // 2 x 16 KB
    __shared__ __align__(16) float sw_s[1024];

    const int tid  = threadIdx.x;
    const int wv   = tid >> 6;
    const int lane = tid & 63;
    const int l15  = lane & 15, lq = lane >> 4;
    const int n0   = blockIdx.x * 64 + wv * 16;   // wave's first token

    reinterpret_cast<float4*>(sw_s)[tid] = reinterpret_cast<const float4*>(swq)[tid];

    // A fragments: one 16-token subtile, coalesced from fragment-linear xf,
    // then pinned into AGPRs so the loads cannot be rematerialized per kt.
    bf16x8 ah[8], al[8];
    {
        const unsigned short* ap = xf + (size_t)(n0 >> 4) * 8192 + lane * 8;
        #pragma unroll
        for (int cs = 0; cs < 8; ++cs) {
            ah[cs] = *(const bf16x8*)(ap + cs * 1024);
            al[cs] = *(const bf16x8*)(ap + cs * 1024 + 512);
        }
        #pragma unroll
        for (int cs = 0; cs < 8; ++cs) {
            asm volatile("" : "+a"(ah[cs]));
            asm volatile("" : "+a"(al[cs]));
        }
    }

    // prologue: stage tile kt=0 (4 KB per wave, linear copy)
    {
        const unsigned short* src = wf + wv * 2048 + lane * 8;
        unsigned short* dst = &btile[0][wv * 2048 + lane * 8];
        #pragma unroll
        for (int j = 0; j < 4; ++j)
            *(bf16x8*)(dst + j * 512) = *(const bf16x8*)(src + j * 512);
    }
    __syncthreads();

    float m1[4], m2[4];
    int   i1[4];
    #pragma unroll
    for (int j = 0; j < 4; ++j) { m1[j] = 1e30f; m2[j] = 1e30f; i1[j] = 0; }

    for (int kt = 0; kt < 64; ++kt) {
        const int cur = kt & 1;

        // issue next tile's global loads early (write-late below)
        bf16x8 stg[4];
        if (kt < 63) {
            const unsigned short* src = wf + (size_t)(kt + 1) * 8192 + wv * 2048 + lane * 8;
            #pragma unroll
            for (int j = 0; j < 4; ++j) stg[j] = *(const bf16x8*)(src + j * 512);
        }

        f32x4 acc = (f32x4){0.f, 0.f, 0.f, 0.f};
        const unsigned short* bp = &btile[cur][lane * 8];
        #pragma unroll
        for (int cs = 0; cs < 8; ++cs) {
            const bf16x8 bh = *(const bf16x8*)(bp + cs * 1024);
            const bf16x8 bl = *(const bf16x8*)(bp + cs * 1024 + 512);
            acc = __builtin_amdgcn_mfma_f32_16x16x32_bf16(ah[cs], bh, acc, 0, 0, 0);
            acc = __builtin_amdgcn_mfma_f32_16x16x32_bf16(al[cs], bh, acc, 0, 0, 0);
            acc = __builtin_amdgcn_mfma_f32_16x16x32_bf16(ah[cs], bl, acc, 0, 0, 0);
        }

        const int k = kt * 16 + l15;      // C/D col = l15
        const float snk = sw_s[k];
        #pragma unroll
        for (int r = 0; r < 4; ++r) {
            const float d = fmaf(-2.f, acc[r], snk);
            if (d < m1[r]) { m2[r] = m1[r]; m1[r] = d; i1[r] = k; }
            else           m2[r] = fminf(m2[r], d);
        }

        // write-late: park next tile into the other buffer, then barrier
        if (kt < 63) {
            unsigned short* dst = &btile[cur ^ 1][wv * 2048 + lane * 8];
            #pragma unroll
            for (int j = 0; j < 4; ++j) *(bf16x8*)(dst + j * 512) = stg[j];
        }
        __syncthreads();
    }

    // reduce across the 16 l15 lanes (lane's codes are ≡ l15 mod 16)
    #pragma unroll
    for (int mm = 1; mm < 16; mm <<= 1) {
        #pragma unroll
        for (int j = 0; j < 4; ++j) {
            const float om1 = __shfl_xor(m1[j], mm);
            const int   oi1 = __shfl_xor(i1[j], mm);
            const float om2 = __shfl_xor(m2[j], mm);
            if (om1 < m1[j]) { m2[j] = fminf(m1[j], om2); m1[j] = om1; i1[j] = oi1; }
            else             { m2[j] = fminf(m2[j], om1); }
        }
    }
    // wave owns all codes for its 16 tokens: winner is final here.
    if (l15 == 0) {
        #pragma unroll
        for (int r = 0; r < 4; ++r) {
            const int n = n0 + lq * 4 + r;   // token row = lq*4 + r
            if (m2[r] - m1[r] > MARGIN) {
                winner[n] = i1[r];
            } else {
                winner[n] = -1;
                const int p = atomicAdd(count, 1);
                flag[p] = n;
            }
        }
    }
}

// ---- resolve v2: np-exact rescore of flagged tokens, coalesced wt loads ----
__global__ __launch_bounds__(256) void vq_resolve2(const float* __restrict__ x,
                                                   const float* __restrict__ wt,
                                                   const float* __restrict__ sxq,
                                                   const float* __restrict__ swq,
                                                   const int* __restrict__ flag,
                                                   const int* __restrict__ count,
                                                   int* __restrict__ winner) {
    __shared__ float xsh[4][256];
    __shared__ int   toks[4];
    __shared__ float r_d[4][4];
    __shared__ int   r_k[4][4];

    const int cnt = *count;
    const int tid = threadIdx.x;
    const int groups = (cnt + 3) >> 2;

    for (int g = blockIdx.x; g < groups; g += gridDim.x) {
        if (tid < 4) toks[tid] = (4 * g + tid < cnt) ? flag[4 * g + tid] : -1;
        __syncthreads();
        #pragma unroll
        for (int i = 0; i < 4; i++) {
            const int n = toks[i];
            float v = 0.f;
            if (n >= 0) {
                const int b = n >> 14, thw = n & 16383;
                v = x[(size_t)b * 4194304 + (size_t)tid * 16384 + thw];
            }
            xsh[i][tid] = v;
        }
        __syncthreads();

        float acc[4][4];   // [q][token]
        #pragma unroll
        for (int q = 0; q < 4; q++)
            #pragma unroll
            for (int i = 0; i < 4; i++) acc[q][i] = 0.f;

        const float* wp = wt + tid;
        #pragma unroll 4
        for (int c = 0; c < 256; c++) {
            const float w0 = wp[(size_t)c * 1024 + 0];
            const float w1 = wp[(size_t)c * 1024 + 256];
            const float w2 = wp[(size_t)c * 1024 + 512];
            const float w3 = wp[(size_t)c * 1024 + 768];
            #pragma unroll
            for (int i = 0; i < 4; i++) {
                const float xc = xsh[i][c];
                acc[0][i] = fmaf(xc, w0, acc[0][i]);
                acc[1][i] = fmaf(xc, w1, acc[1][i]);
                acc[2][i] = fmaf(xc, w2, acc[2][i]);
                acc[3][i] = fmaf(xc, w3, acc[3][i]);
            }
        }

        // np distances + lexicographic (d,k) argmin per token
        const float swk[4] = {swq[tid], swq[tid + 256], swq[tid + 512], swq[tid + 768]};
        #pragma unroll
        for (int i = 0; i < 4; i++) {
            const int n = toks[i];
            float bd = 1e30f;
            int   bk = 0x7fffffff;
            if (n >= 0) {
                const float sx = sxq[n];
                #pragma unroll
                for (int q = 0; q < 4; q++) {
                    const int k = tid + 256 * q;
                    const float s1 = sx + swk[q];
                    const float d  = fmaf(-2.f, acc[q][i], s1);
                    if (d < bd || (d == bd && k < bk)) { bd = d; bk = k; }
                }
            }
            #pragma unroll
            for (int mm = 1; mm < 64; mm <<= 1) {
                const float od = __shfl_xor(bd, mm);
                const int   ok = __shfl_xor(bk, mm);
                if (od < bd || (od == bd && ok < bk)) { bd = od; bk = ok; }
            }
            if ((tid & 63) == 0) { r_d[tid >> 6][i] = bd; r_k[tid >> 6][i] = bk; }
        }
        __syncthreads();
        if (tid < 4) {
            const int n = toks[tid];
            if (n >= 0) {
                float bd = r_d[0][tid]; int bk = r_k[0][tid];
                #pragma unroll
                for (int wv = 1; wv < 4; wv++) {
                    const float od = r_d[wv][tid];
                    const int   ok = r_k[wv][tid];
                    if (od < bd || (od == bd && ok < bk)) { bd = od; bk = ok; }
                }
                winner[n] = bk;
            }
        }
        __syncthreads();
    }
}

// ---- gather ----
__global__ __launch_bounds__(256) void vq_gather(const float* __restrict__ w,
                                                 const int* __restrict__ winner,
                                                 float* __restrict__ out) {
    const size_t idx = (size_t)blockIdx.x * 256 + threadIdx.x;
    const int n = (int)(idx >> 6);
    const int c4 = (int)(idx & 63);
    reinterpret_cast<float4*>(out)[idx] =
        reinterpret_cast<const float4*>(w + (size_t)winner[n] * 256)[c4];
}

// ================= R3 fallback (proven-correct) =================
#define TPB 32
__global__ __launch_bounds__(256) void vq_main(const float* __restrict__ x,
                                               const float* __restrict__ sxq,
                                               const float* __restrict__ swq,
                                               const float* __restrict__ wt,
                                               const float* __restrict__ weight,
                                               float* __restrict__ out) {
    __shared__ __align__(16) float xs[256 * TPB];
    __shared__ float wn[1024];
    __shared__ float sxs[TPB];
    __shared__ float red_s[4][TPB];
    __shared__ int   red_i[4][TPB];
    __shared__ int   fidx[TPB];

    const int tid = threadIdx.x;
    const int n0 = blockIdx.x * TPB;
    const int b = n0 >> 14, thw = n0 & 16383;
    const float* xb = x + (size_t)b * 4194304 + thw;

    for (int i = tid; i < 256 * TPB; i += 256) {
        int t = i & (TPB - 1);
        int c = i >> 5;
        xs[c * TPB + t] = xb[(size_t)c * 16384 + t];
    }
    for (int i = tid; i < 1024; i += 256) wn[i] = swq[i];
    if (tid < TPB) sxs[tid] = sxq[n0 + tid];
    __syncthreads();

    const int lane = tid & 63, wv = tid >> 6;
    const int tg = lane & 7, cg = lane >> 3;
    float sxr[4];
    #pragma unroll
    for (int j = 0; j < 4; j++) sxr[j] = sxs[4 * tg + j];
    float bestS[4]; int bestI[4];
    #pragma unroll
    for (int j = 0; j < 4; j++) { bestS[j] = 1e30f; bestI[j] = 0x7fffffff; }

    for (int kb = 0; kb < 1024; kb += 256) {
        const int kbase = kb + 64 * wv + 8 * cg;
        float acc[4][8];
        #pragma unroll
        for (int j = 0; j < 4; j++)
            #pragma unroll
            for (int q = 0; q < 8; q++) acc[j][q] = 0.f;
        const float* wtp = wt + kbase;
        #pragma unroll 4
        for (int c = 0; c < 256; c++) {
            const float4 xv = *reinterpret_cast<const float4*>(&xs[c * TPB + 4 * tg]);
            const float4 w0 = *reinterpret_cast<const float4*>(wtp + (size_t)c * 1024);
            const float4 w1 = *reinterpret_cast<const float4*>(wtp + (size_t)c * 1024 + 4);
            const float xr[4] = {xv.x, xv.y, xv.z, xv.w};
            const float wr[8] = {w0.x, w0.y, w0.z, w0.w, w1.x, w1.y, w1.z, w1.w};
            #pragma unroll
            for (int j = 0; j < 4; j++)
                #pragma unroll
                for (int q = 0; q < 8; q++)
                    acc[j][q] = fmaf(xr[j], wr[q], acc[j][q]);
        }
        #pragma unroll
        for (int q = 0; q < 8; q++) {
            const int k = kbase + q;
            const float wnk = wn[k];
            #pragma unroll
            for (int j = 0; j < 4; j++) {
                const float s1 = sxr[j] + wnk;
                const float d = fmaf(-2.f, acc[j][q], s1);
                if (d < bestS[j]) { bestS[j] = d; bestI[j] = k; }
            }
        }
    }
    #pragma unroll
    for (int m = 8; m < 64; m <<= 1) {
        #pragma unroll
        for (int j = 0; j < 4; j++) {
            const float os = __shfl_xor(bestS[j], m);
            const int   oi = __shfl_xor(bestI[j], m);
            if (os < bestS[j] || (os == bestS[j] && oi < bestI[j])) {
                bestS[j] = os; bestI[j] = oi;
            }
        }
    }
    if (cg == 0) {
        #pragma unroll
        for (int j = 0; j < 4; j++) {
            red_s[wv][4 * tg + j] = bestS[j];
            red_i[wv][4 * tg + j] = bestI[j];
        }
    }
    __syncthreads();
    if (tid < TPB) {
        float bs = red_s[0][tid]; int bi = red_i[0][tid];
        #pragma unroll
        for (int w2 = 1; w2 < 4; w2++) {
            const float s2 = red_s[w2][tid];
            const int   i2 = red_i[w2][tid];
            if (s2 < bs || (s2 == bs && i2 < bi)) { bs = s2; bi = i2; }
        }
        fidx[tid] = bi;
    }
    __syncthreads();
    for (int i = tid; i < TPB * 256; i += 256) {
        const int t = i >> 8, c = i & 255;
        out[(size_t)(n0 + t) * 256 + c] = weight[(size_t)fidx[t] * 256 + c];
    }
}

// ================= launch =================
extern "C" void kernel_launch(void* const* d_in, const int* in_sizes, int n_in,
                              void* d_out, int out_size, void* d_ws, size_t ws_size,
                              hipStream_t stream) {
    const float* x = (const float*)d_in[0];
    const float* w = (const float*)d_in[1];
    float* out = (float*)d_out;

    char* p = (char*)d_ws;
    int*   count  = (int*)p;                         p += 256;
    int*   winner = (int*)p;                         p += 65536 * 4;
    int*   flag   = (int*)p;                         p += 65536 * 4;
    float* sxq    = (float*)p;                       p += 65536 * 4;
    float* swq    = (float*)p;                       p += 1024 * 4;
    float* wt     = (float*)p;                       p += 262144 * 4;
    unsigned short* wf = (unsigned short*)p;         p += 524288 * 2;
    unsigned short* xf = (unsigned short*)p;         p += 33554432 * 2;
    const size_t need_fast = (size_t)(p - (char*)d_ws);

    if (ws_size >= need_fast) {
        hipMemsetAsync(count, 0, 4, stream);
        vq_sxq<<<256, 256, 0, stream>>>(x, sxq);
        vq_swq<<<4, 256, 0, stream>>>(w, swq);
        vq_wt<<<1024, 64, 0, stream>>>(w, wt);
        vq_wfrag<<<128, 256, 0, stream>>>(w, wf);
        vq_split_x<<<4096, 256, 0, stream>>>(x, xf);
        vq_screen6<<<1024, 256, 0, stream>>>(xf, wf, swq, winner, flag, count);
        vq_resolve2<<<1024, 256, 0, stream>>>(x, wt, sxq, swq, flag, count, winner);
        vq_gather<<<16384, 256, 0, stream>>>(w, winner, out);
    } else {
        // proven R3 fallback (needs ~1.3 MB)
        float* sxq2 = (float*)d_ws;
        float* swq2 = sxq2 + 65536;
        float* wt2  = swq2 + 1024;
        vq_sxq<<<256, 256, 0, stream>>>(x, sxq2);
        vq_swq<<<4, 256, 0, stream>>>(w, swq2);
        vq_wt<<<1024, 64, 0, stream>>>(w, wt2);
        vq_main<<<65536 / TPB, 256, 0, stream>>>(x, sxq2, swq2, wt2, w, out);
    }
}